// Round 1
// baseline (1269.283 us; speedup 1.0000x reference)
//
#include <hip/hip_runtime.h>

constexpr int NA = 50000, NB = 50000;
constexpr int EMB = 16, HID = 64;
constexpr int NE = 800000;
constexpr int CAP = 64;

// ---------------- K0: fold embedding tables through pre_W ----------------
// Output layout: T[type][col][fd*32+bin]  (2 * 64 * 256 floats)
__global__ void k_tables(const float* __restrict__ embA, const float* __restrict__ embB,
                         const float* __restrict__ preWA, const float* __restrict__ preWB,
                         float* __restrict__ T) {
  int id = blockIdx.x * 256 + threadIdx.x;  // 0..32767
  int type = id >> 14;
  int rem = id & 16383;
  int col = rem >> 8;       // 0..63
  int fdbin = rem & 255;    // fd*32+bin
  int fd = fdbin >> 5;
  const float* emb = type ? embB : embA;
  const float* W = type ? preWB : preWA;
  const float* e = emb + fdbin * EMB;
  const float* w = W + (fd * EMB) * HID + col;
  float s = 0.f;
#pragma unroll
  for (int j = 0; j < EMB; ++j) s += e[j] * w[j * HID];
  T[id] = s;  // coalesced
}

// ---------------- K1: x0 = relu(bias + sum_fd T[fd][bin_fd][:]) ----------------
// 256 threads, 64 rows/block, 4 threads per row (16 cols each).
// LDS holds T swizzled: float addr = col*256 + ((fdbin + 8*(col>>4)) & 255)
__global__ void __launch_bounds__(256) k_x0(const int* __restrict__ x,
                                            const float* __restrict__ T,
                                            const float* __restrict__ bias,
                                            float* __restrict__ x0, int N) {
  extern __shared__ float Tl[];  // 16384 floats = 64KB
  const float4* Tg = (const float4*)T;
  float4* Ts = (float4*)Tl;
  for (int i = threadIdx.x; i < 4096; i += 256) {
    int col = i >> 6, b4 = i & 63;
    Ts[col * 64 + ((b4 + 2 * (col >> 4)) & 63)] = Tg[i];
  }
  __syncthreads();
  int t = threadIdx.x;
  int r = t >> 2, q = t & 3;
  int row = blockIdx.x * 64 + r;
  bool valid = row < N;
  int arow = valid ? row : (N - 1);
  const int4* xp = (const int4*)(x + arow * 8);
  int4 xa = xp[0], xb = xp[1];
  int bins[8] = {xa.x, xa.y, xa.z, xa.w, xb.x, xb.y, xb.z, xb.w};
  int c0 = q * 16;
  float acc[16];
#pragma unroll
  for (int j = 0; j < 16; ++j) acc[j] = bias[c0 + j];
#pragma unroll
  for (int fd = 0; fd < 8; ++fd) {
    int sb = ((fd * 32 + bins[fd]) + 8 * q) & 255;  // bank = (bin+8q)%32 -> spread
#pragma unroll
    for (int j = 0; j < 16; ++j) acc[j] += Tl[(c0 + j) * 256 + sb];
  }
  if (valid) {
    float* o = x0 + (size_t)row * 64 + c0;
#pragma unroll
    for (int j = 0; j < 16; ++j) o[j] = fmaxf(acc[j], 0.f);
  }
}

// ---------------- K2: edge scatter into padded CSR buckets ----------------
__global__ void k_scatter(const int* __restrict__ ei, int* __restrict__ cursor,
                          int* __restrict__ slots, int E) {
  int e = blockIdx.x * 256 + threadIdx.x;
  if (e >= E) return;
  int src = ei[e];
  int dst = ei[E + e];
  int pos = atomicAdd(cursor + dst, 1);
  if (pos < CAP) slots[dst * CAP + pos] = src;
}

// ---------------- K3: segment mean (16 lanes per dst) ----------------
__global__ void k_mean(const int* __restrict__ slots, const int* __restrict__ cursor,
                       const float* __restrict__ x0, float* __restrict__ m, int N) {
  int t = threadIdx.x;
  int lane = t & 15, local = t >> 4;
  int dst = blockIdx.x * 16 + local;
  if (dst >= N) return;
  int deg = cursor[dst];
  int cnt = min(deg, CAP);
  const int* sl = slots + dst * CAP;
  float a0 = 0.f, a1 = 0.f, a2 = 0.f, a3 = 0.f;
  for (int i = 0; i < cnt; ++i) {
    int src = sl[i];
    const float* rr = x0 + (size_t)src * 64 + lane;
    a0 += rr[0]; a1 += rr[16]; a2 += rr[32]; a3 += rr[48];
  }
  float inv = 1.f / (float)(deg > 1 ? deg : 1);
  float* mm = m + (size_t)dst * 64 + lane;
  mm[0] = a0 * inv; mm[16] = a1 * inv; mm[32] = a2 * inv; mm[48] = a3 * inv;
}

// ---------------- K4a: fused node chain for A: h -> z -> (fl, y_ba, y_aa) ----------------
__global__ void __launch_bounds__(256) k_nodeA(
    const float* __restrict__ x0A, const float* __restrict__ m1, const float* __restrict__ m2,
    const float* __restrict__ Wl1, const float* __restrict__ bl1, const float* __restrict__ Wr1,
    const float* __restrict__ Wl2, const float* __restrict__ bl2, const float* __restrict__ Wr2,
    const float* __restrict__ projW, const float* __restrict__ projb,
    const float* __restrict__ headW, const float* __restrict__ headb,
    const float* __restrict__ bilW1, const float* __restrict__ bilW2,
    float* __restrict__ zout, float* __restrict__ flout,
    float* __restrict__ y1out, float* __restrict__ y2out, int N) {
  __shared__ float hs[64][65];
  __shared__ float zsh[64][33];
  int t = threadIdx.x;
  int r = t >> 2, q = t & 3;
  int row = blockIdx.x * 64 + r;
  bool valid = row < N;
  int arow = valid ? row : (N - 1);
  const float* xr = x0A + (size_t)arow * 64;
  const float* m1r = m1 + (size_t)arow * 64;
  const float* m2r = m2 + (size_t)arow * 64;
  int c0 = q * 16;
  float acc[16];
#pragma unroll
  for (int j = 0; j < 16; ++j) acc[j] = 0.f;
#pragma unroll 4
  for (int k = 0; k < 64; ++k) {
    float a0 = xr[k], a1 = m1r[k], a2 = m2r[k];
    const float* p1 = Wl1 + k * 64 + c0;
    const float* p2 = Wl2 + k * 64 + c0;
    const float* p3 = Wr1 + k * 64 + c0;
    const float* p4 = Wr2 + k * 64 + c0;
#pragma unroll
    for (int j = 0; j < 16; ++j)
      acc[j] += a1 * p1[j] + a2 * p2[j] + a0 * (p3[j] + p4[j]);
  }
#pragma unroll
  for (int j = 0; j < 16; ++j)
    hs[r][c0 + j] = 0.5f * (acc[j] + bl1[c0 + j] + bl2[c0 + j]);
  __syncthreads();
  // proj -> z (relu); 8 cols per thread
  int cz = q * 8;
  float za[8];
#pragma unroll
  for (int j = 0; j < 8; ++j) za[j] = projb[cz + j];
#pragma unroll 4
  for (int k = 0; k < 64; ++k) {
    float h = hs[r][k];
    const float* pw = projW + k * 32 + cz;
#pragma unroll
    for (int j = 0; j < 8; ++j) za[j] += h * pw[j];
  }
#pragma unroll
  for (int j = 0; j < 8; ++j) {
    za[j] = fmaxf(za[j], 0.f);
    zsh[r][cz + j] = za[j];
  }
  if (valid) {
    float* zo = zout + (size_t)row * 32 + cz;
#pragma unroll
    for (int j = 0; j < 8; ++j) zo[j] = za[j];
  }
  __syncthreads();
  // bilinear precompute y[i] = sum_k W[i][k] * z[k]  (dst-side transforms)
#pragma unroll
  for (int i = 0; i < 8; ++i) {
    const float* w1 = bilW1 + (cz + i) * 32;
    const float* w2 = bilW2 + (cz + i) * 32;
    float s1 = 0.f, s2 = 0.f;
#pragma unroll
    for (int k = 0; k < 32; ++k) {
      float zv = zsh[r][k];
      s1 += w1[k] * zv;
      s2 += w2[k] * zv;
    }
    if (valid) {
      y1out[(size_t)row * 32 + cz + i] = s1;
      y2out[(size_t)row * 32 + cz + i] = s2;
    }
  }
  // head -> fl (256 cols, 4 chunks of 16 per thread)
  for (int ch = 0; ch < 4; ++ch) {
    int cf = ch * 64 + c0;
    float f[16];
#pragma unroll
    for (int j = 0; j < 16; ++j) f[j] = headb[cf + j];
#pragma unroll 4
    for (int k = 0; k < 32; ++k) {
      float zv = zsh[r][k];
      const float* hw = headW + k * 256 + cf;
#pragma unroll
      for (int j = 0; j < 16; ++j) f[j] += zv * hw[j];
    }
    if (valid) {
      float* fo = flout + (size_t)row * 256 + cf;
#pragma unroll
      for (int j = 0; j < 16; ++j) fo[j] = f[j];
    }
  }
}

// ---------------- K4b: fused node chain for B ----------------
__global__ void __launch_bounds__(256) k_nodeB(
    const float* __restrict__ x0B, const float* __restrict__ m,
    const float* __restrict__ Wl, const float* __restrict__ bl, const float* __restrict__ Wr,
    const float* __restrict__ projW, const float* __restrict__ projb,
    const float* __restrict__ headW, const float* __restrict__ headb,
    const float* __restrict__ bilW,
    float* __restrict__ zout, float* __restrict__ flout,
    float* __restrict__ yout, int N) {
  __shared__ float hs[64][65];
  __shared__ float zsh[64][33];
  int t = threadIdx.x;
  int r = t >> 2, q = t & 3;
  int row = blockIdx.x * 64 + r;
  bool valid = row < N;
  int arow = valid ? row : (N - 1);
  const float* xr = x0B + (size_t)arow * 64;
  const float* mr = m + (size_t)arow * 64;
  int c0 = q * 16;
  float acc[16];
#pragma unroll
  for (int j = 0; j < 16; ++j) acc[j] = bl[c0 + j];
#pragma unroll 4
  for (int k = 0; k < 64; ++k) {
    float a0 = xr[k], a1 = mr[k];
    const float* pl = Wl + k * 64 + c0;
    const float* pr = Wr + k * 64 + c0;
#pragma unroll
    for (int j = 0; j < 16; ++j) acc[j] += a1 * pl[j] + a0 * pr[j];
  }
#pragma unroll
  for (int j = 0; j < 16; ++j) hs[r][c0 + j] = acc[j];
  __syncthreads();
  int cz = q * 8;
  float za[8];
#pragma unroll
  for (int j = 0; j < 8; ++j) za[j] = projb[cz + j];
#pragma unroll 4
  for (int k = 0; k < 64; ++k) {
    float h = hs[r][k];
    const float* pw = projW + k * 32 + cz;
#pragma unroll
    for (int j = 0; j < 8; ++j) za[j] += h * pw[j];
  }
#pragma unroll
  for (int j = 0; j < 8; ++j) {
    za[j] = fmaxf(za[j], 0.f);
    zsh[r][cz + j] = za[j];
  }
  if (valid) {
    float* zo = zout + (size_t)row * 32 + cz;
#pragma unroll
    for (int j = 0; j < 8; ++j) zo[j] = za[j];
  }
  __syncthreads();
#pragma unroll
  for (int i = 0; i < 8; ++i) {
    const float* w1 = bilW + (cz + i) * 32;
    float s1 = 0.f;
#pragma unroll
    for (int k = 0; k < 32; ++k) s1 += w1[k] * zsh[r][k];
    if (valid) yout[(size_t)row * 32 + cz + i] = s1;
  }
  for (int ch = 0; ch < 4; ++ch) {
    int cf = ch * 64 + c0;
    float f[16];
#pragma unroll
    for (int j = 0; j < 16; ++j) f[j] = headb[cf + j];
#pragma unroll 4
    for (int k = 0; k < 32; ++k) {
      float zv = zsh[r][k];
      const float* hw = headW + k * 256 + cf;
#pragma unroll
      for (int j = 0; j < 16; ++j) f[j] += zv * hw[j];
    }
    if (valid) {
      float* fo = flout + (size_t)row * 256 + cf;
#pragma unroll
      for (int j = 0; j < 16; ++j) fo[j] = f[j];
    }
  }
}

// ---------------- K5: bilinear edge scores: s = z_src . y_dst + b ----------------
__global__ void k_bil(const int* __restrict__ ei, const float* __restrict__ zsrc,
                      const float* __restrict__ ydst, const float* __restrict__ b,
                      float* __restrict__ s, int E) {
  int e = blockIdx.x * 256 + threadIdx.x;
  if (e >= E) return;
  int si = ei[e], di = ei[E + e];
  const float4* zp = (const float4*)(zsrc + (size_t)si * 32);
  const float4* yp = (const float4*)(ydst + (size_t)di * 32);
  float acc = 0.f;
#pragma unroll
  for (int i = 0; i < 8; ++i) {
    float4 a = zp[i], c = yp[i];
    acc += a.x * c.x + a.y * c.y + a.z * c.z + a.w * c.w;
  }
  s[e] = acc + b[0];
}

extern "C" void kernel_launch(void* const* d_in, const int* in_sizes, int n_in,
                              void* d_out, int out_size, void* d_ws, size_t ws_size,
                              hipStream_t stream) {
  const int* xA = (const int*)d_in[0];
  const int* xB = (const int*)d_in[1];
  const int* ei_ab = (const int*)d_in[2];
  const int* ei_ba = (const int*)d_in[3];
  const int* ei_aa = (const int*)d_in[4];
  const float* embA = (const float*)d_in[5];
  const float* embB = (const float*)d_in[6];
  const float* preWA = (const float*)d_in[7];
  const float* prebA = (const float*)d_in[8];
  const float* preWB = (const float*)d_in[9];
  const float* prebB = (const float*)d_in[10];
  const float* Wl_ab = (const float*)d_in[11];
  const float* bl_ab = (const float*)d_in[12];
  const float* Wr_ab = (const float*)d_in[13];
  const float* Wl_ba = (const float*)d_in[14];
  const float* bl_ba = (const float*)d_in[15];
  const float* Wr_ba = (const float*)d_in[16];
  const float* Wl_aa = (const float*)d_in[17];
  const float* bl_aa = (const float*)d_in[18];
  const float* Wr_aa = (const float*)d_in[19];
  const float* projWA = (const float*)d_in[20];
  const float* projbA = (const float*)d_in[21];
  const float* projWB = (const float*)d_in[22];
  const float* projbB = (const float*)d_in[23];
  const float* headWA = (const float*)d_in[24];
  const float* headbA = (const float*)d_in[25];
  const float* headWB = (const float*)d_in[26];
  const float* headbB = (const float*)d_in[27];
  const float* bilW_ab = (const float*)d_in[28];
  const float* bilb_ab = (const float*)d_in[29];
  const float* bilW_ba = (const float*)d_in[30];
  const float* bilb_ba = (const float*)d_in[31];
  const float* bilW_aa = (const float*)d_in[32];
  const float* bilb_aa = (const float*)d_in[33];

  // output layout (flat concat, float32)
  float* out = (float*)d_out;
  float* zA = out;                      // 50000*32
  float* zB = out + 1600000;            // 50000*32
  float* flA = out + 3200000;           // 50000*256
  float* flB = out + 16000000;          // 50000*256
  float* s_ab = out + 28800000;         // 800000
  float* s_ba = out + 29600000;
  float* s_aa = out + 30400000;

  // workspace layout (~84 MB)
  float* ws = (float*)d_ws;
  float* T = ws;                               // 32768
  float* x0A = ws + 32768;                     // 3.2M
  float* x0B = x0A + (size_t)NA * 64;          // 3.2M
  float* mab = x0B + (size_t)NB * 64;          // 3.2M (dst=B)
  float* mba = mab + (size_t)NB * 64;          // 3.2M (dst=A)
  float* maa = mba + (size_t)NA * 64;          // 3.2M (dst=A)
  float* yabB = maa + (size_t)NA * 64;         // 1.6M
  float* ybaA = yabB + (size_t)NB * 32;        // 1.6M
  float* yaaA = ybaA + (size_t)NA * 32;        // 1.6M
  int* cur = (int*)(yaaA + (size_t)NA * 32);   // 150000 ints
  int* cur_ab = cur;
  int* cur_ba = cur + NB;
  int* cur_aa = cur + NB + NA;
  // slot buckets live in fl_A's region of d_out (dead until k_nodeA runs)
  int* slots = (int*)flA;                      // 50000*64 ints = 12.8 MB

  hipMemsetAsync(cur, 0, (size_t)(NA + NB + NA) * sizeof(int), stream);
  k_tables<<<128, 256, 0, stream>>>(embA, embB, preWA, preWB, T);
  k_x0<<<(NA + 63) / 64, 256, 65536, stream>>>(xA, T, prebA, x0A, NA);
  k_x0<<<(NB + 63) / 64, 256, 65536, stream>>>(xB, T + 16384, prebB, x0B, NB);

  // ab: src=A nodes, dst=B nodes
  k_scatter<<<NE / 256, 256, 0, stream>>>(ei_ab, cur_ab, slots, NE);
  k_mean<<<(NB + 15) / 16, 256, 0, stream>>>(slots, cur_ab, x0A, mab, NB);
  // ba: src=B nodes, dst=A nodes
  k_scatter<<<NE / 256, 256, 0, stream>>>(ei_ba, cur_ba, slots, NE);
  k_mean<<<(NA + 15) / 16, 256, 0, stream>>>(slots, cur_ba, x0B, mba, NA);
  // aa: src=A, dst=A
  k_scatter<<<NE / 256, 256, 0, stream>>>(ei_aa, cur_aa, slots, NE);
  k_mean<<<(NA + 15) / 16, 256, 0, stream>>>(slots, cur_aa, x0A, maa, NA);

  k_nodeA<<<(NA + 63) / 64, 256, 0, stream>>>(
      x0A, mba, maa, Wl_ba, bl_ba, Wr_ba, Wl_aa, bl_aa, Wr_aa,
      projWA, projbA, headWA, headbA, bilW_ba, bilW_aa,
      zA, flA, ybaA, yaaA, NA);
  k_nodeB<<<(NB + 63) / 64, 256, 0, stream>>>(
      x0B, mab, Wl_ab, bl_ab, Wr_ab, projWB, projbB, headWB, headbB, bilW_ab,
      zB, flB, yabB, NB);

  k_bil<<<NE / 256, 256, 0, stream>>>(ei_ab, zA, yabB, bilb_ab, s_ab, NE);
  k_bil<<<NE / 256, 256, 0, stream>>>(ei_ba, zB, ybaA, bilb_ba, s_ba, NE);
  k_bil<<<NE / 256, 256, 0, stream>>>(ei_aa, zA, yaaA, bilb_aa, s_aa, NE);
}

// Round 2
// 729.113 us; speedup vs baseline: 1.7409x; 1.7409x over previous
//
#include <hip/hip_runtime.h>

constexpr int NA = 50000, NB = 50000;
constexpr int EMB = 16, HID = 64;
constexpr int NE = 800000;
constexpr int CAP = 64;

// ---------------- K0: fold embedding tables through pre_W ----------------
// Output layout: T[type][col][fd*32+bin]  (2 * 64 * 256 floats)
__global__ void k_tables(const float* __restrict__ embA, const float* __restrict__ embB,
                         const float* __restrict__ preWA, const float* __restrict__ preWB,
                         float* __restrict__ T) {
  int id = blockIdx.x * 256 + threadIdx.x;  // 0..32767
  int type = id >> 14;
  int rem = id & 16383;
  int col = rem >> 8;       // 0..63
  int fdbin = rem & 255;    // fd*32+bin
  int fd = fdbin >> 5;
  const float* emb = type ? embB : embA;
  const float* W = type ? preWB : preWA;
  const float* e = emb + fdbin * EMB;
  const float* w = W + (fd * EMB) * HID + col;
  float s = 0.f;
#pragma unroll
  for (int j = 0; j < EMB; ++j) s += e[j] * w[j * HID];
  T[id] = s;  // coalesced
}

// ---------------- K0b: prep folded weights for node kernels ----------------
// prep layout (floats): WsA[4096] | Wl1h[4096] | Wl2h[4096] | bhA[64]
//                       | bilT_ba[1024] | bilT_aa[1024] | bilT_ab[1024]
__global__ void k_prep(const float* __restrict__ Wr_ba, const float* __restrict__ Wr_aa,
                       const float* __restrict__ Wl_ba, const float* __restrict__ Wl_aa,
                       const float* __restrict__ bl_ba, const float* __restrict__ bl_aa,
                       const float* __restrict__ bilW_ba, const float* __restrict__ bilW_aa,
                       const float* __restrict__ bilW_ab, float* __restrict__ prep) {
  int i = blockIdx.x * 256 + threadIdx.x;  // 4096 threads
  float* WsA = prep;
  float* Wl1h = prep + 4096;
  float* Wl2h = prep + 8192;
  float* bhA = prep + 12288;
  float* bT_ba = prep + 12352;
  float* bT_aa = prep + 13376;
  float* bT_ab = prep + 14400;
  if (i < 4096) {
    WsA[i] = 0.5f * (Wr_ba[i] + Wr_aa[i]);
    Wl1h[i] = 0.5f * Wl_ba[i];
    Wl2h[i] = 0.5f * Wl_aa[i];
  }
  if (i < 64) bhA[i] = 0.5f * (bl_ba[i] + bl_aa[i]);
  if (i < 1024) {
    int k = i >> 5, c = i & 31;       // bT[k*32+c] = W[c*32+k]
    bT_ba[i] = bilW_ba[c * 32 + k];
    bT_aa[i] = bilW_aa[c * 32 + k];
    bT_ab[i] = bilW_ab[c * 32 + k];
  }
}

// ---------------- K1: x0 = relu(bias + sum_fd T[fd][bin_fd][:]) ----------------
__global__ void __launch_bounds__(256) k_x0(const int* __restrict__ x,
                                            const float* __restrict__ T,
                                            const float* __restrict__ bias,
                                            float* __restrict__ x0, int N) {
  extern __shared__ float Tl[];  // 16384 floats = 64KB
  const float4* Tg = (const float4*)T;
  float4* Ts = (float4*)Tl;
  for (int i = threadIdx.x; i < 4096; i += 256) {
    int col = i >> 6, b4 = i & 63;
    Ts[col * 64 + ((b4 + 2 * (col >> 4)) & 63)] = Tg[i];
  }
  __syncthreads();
  int t = threadIdx.x;
  int r = t >> 2, q = t & 3;
  int row = blockIdx.x * 64 + r;
  bool valid = row < N;
  int arow = valid ? row : (N - 1);
  const int4* xp = (const int4*)(x + arow * 8);
  int4 xa = xp[0], xb = xp[1];
  int bins[8] = {xa.x, xa.y, xa.z, xa.w, xb.x, xb.y, xb.z, xb.w};
  int c0 = q * 16;
  float acc[16];
#pragma unroll
  for (int j = 0; j < 16; ++j) acc[j] = bias[c0 + j];
#pragma unroll
  for (int fd = 0; fd < 8; ++fd) {
    int sb = ((fd * 32 + bins[fd]) + 8 * q) & 255;
#pragma unroll
    for (int j = 0; j < 16; ++j) acc[j] += Tl[(c0 + j) * 256 + sb];
  }
  if (valid) {
    float* o = x0 + (size_t)row * 64 + c0;
#pragma unroll
    for (int j = 0; j < 16; ++j) o[j] = fmaxf(acc[j], 0.f);
  }
}

// ---------------- K2: edge scatter into padded CSR buckets ----------------
__global__ void k_scatter(const int* __restrict__ ei, int* __restrict__ cursor,
                          int* __restrict__ slots, int E) {
  int e = blockIdx.x * 256 + threadIdx.x;
  if (e >= E) return;
  int src = ei[e];
  int dst = ei[E + e];
  int pos = atomicAdd(cursor + dst, 1);
  if (pos < CAP) slots[dst * CAP + pos] = src;
}

// ---------------- K3: segment mean (16 lanes per dst) ----------------
__global__ void k_mean(const int* __restrict__ slots, const int* __restrict__ cursor,
                       const float* __restrict__ x0, float* __restrict__ m, int N) {
  int t = threadIdx.x;
  int lane = t & 15, local = t >> 4;
  int dst = blockIdx.x * 16 + local;
  if (dst >= N) return;
  int deg = cursor[dst];
  int cnt = min(deg, CAP);
  const int* sl = slots + dst * CAP;
  float a0 = 0.f, a1 = 0.f, a2 = 0.f, a3 = 0.f;
  for (int i = 0; i < cnt; ++i) {
    int src = sl[i];
    const float* rr = x0 + (size_t)src * 64 + lane;
    a0 += rr[0]; a1 += rr[16]; a2 += rr[32]; a3 += rr[48];
  }
  float inv = 1.f / (float)(deg > 1 ? deg : 1);
  float* mm = m + (size_t)dst * 64 + lane;
  mm[0] = a0 * inv; mm[16] = a1 * inv; mm[32] = a2 * inv; mm[48] = a3 * inv;
}

// ---------------- K4a: node chain A. wave=16-col group, lane=row. ----------------
// Weights via wave-uniform s_loads; inputs via LDS. h,z round-trip through LDS.
__global__ void __launch_bounds__(256) k_nodeA(
    const float* __restrict__ x0A, const float* __restrict__ m1,
    const float* __restrict__ m2, const float* __restrict__ prep,
    const float* __restrict__ projW, const float* __restrict__ projb,
    const float* __restrict__ headW, const float* __restrict__ headb,
    float* __restrict__ zout, float* __restrict__ flout,
    float* __restrict__ y1out, float* __restrict__ y2out, int N) {
  __shared__ float xs[64][65];   // x0 tile -> later h tile
  __shared__ float m1s[64][65];  // m1 tile -> later z tile
  __shared__ float m2s[64][65];  // m2 tile
  const float* WsA = prep;         // x0 weight (0.5*(Wr_ba+Wr_aa))
  const float* Wl1h = prep + 4096; // 0.5*Wl_ba
  const float* Wl2h = prep + 8192; // 0.5*Wl_aa
  const float* bhA = prep + 12288;
  const float* bT1 = prep + 12352; // bilT_ba [k][i]
  const float* bT2 = prep + 13376; // bilT_aa [k][i]

  int t = threadIdx.x;
  int lane = t & 63;
  int w = __builtin_amdgcn_readfirstlane(t >> 6);  // 0..3, wave-uniform SGPR
  int row0 = blockIdx.x * 64;
  int row = row0 + lane;
  bool valid = row < N;

  // stage inputs (clamped rows for tail block)
  for (int i = t; i < 1024; i += 256) {
    int r = i >> 4, c4 = i & 15;
    int grow = min(row0 + r, N - 1);
    float4 v1 = *((const float4*)(x0A + (size_t)grow * 64) + c4);
    float4 v2 = *((const float4*)(m1 + (size_t)grow * 64) + c4);
    float4 v3 = *((const float4*)(m2 + (size_t)grow * 64) + c4);
    int b = c4 * 4;
    xs[r][b] = v1.x; xs[r][b + 1] = v1.y; xs[r][b + 2] = v1.z; xs[r][b + 3] = v1.w;
    m1s[r][b] = v2.x; m1s[r][b + 1] = v2.y; m1s[r][b + 2] = v2.z; m1s[r][b + 3] = v2.w;
    m2s[r][b] = v3.x; m2s[r][b + 1] = v3.y; m2s[r][b + 2] = v3.z; m2s[r][b + 3] = v3.w;
  }
  __syncthreads();

  // ---- h = x0@WsA + m1@Wl1h + m2@Wl2h + bhA ----
  int c0 = w * 16;
  float acc[16];
#pragma unroll
  for (int j = 0; j < 16; ++j) acc[j] = 0.f;
#pragma unroll 2
  for (int k = 0; k < 64; ++k) {
    float a0 = xs[lane][k], a1 = m1s[lane][k], a2 = m2s[lane][k];
    const float* p0 = WsA + k * 64 + c0;   // wave-uniform -> s_load
    const float* p1 = Wl1h + k * 64 + c0;
    const float* p2 = Wl2h + k * 64 + c0;
#pragma unroll
    for (int j = 0; j < 16; ++j)
      acc[j] += a0 * p0[j] + a1 * p1[j] + a2 * p2[j];
  }
  __syncthreads();  // everyone done reading xs
#pragma unroll
  for (int j = 0; j < 16; ++j) xs[lane][c0 + j] = acc[j] + bhA[c0 + j];
  __syncthreads();

  // ---- z = relu(h@projW + projb), 8 cols per wave ----
  int cz = w * 8;
  float za[8];
#pragma unroll
  for (int j = 0; j < 8; ++j) za[j] = projb[cz + j];
#pragma unroll 4
  for (int k = 0; k < 64; ++k) {
    float h = xs[lane][k];
    const float* pw = projW + k * 32 + cz;
#pragma unroll
    for (int j = 0; j < 8; ++j) za[j] += h * pw[j];
  }
#pragma unroll
  for (int j = 0; j < 8; ++j) {
    za[j] = fmaxf(za[j], 0.f);
    m1s[lane][cz + j] = za[j];
  }
  if (valid) {
    float* zo = zout + (size_t)row * 32 + cz;
#pragma unroll
    for (int j = 0; j < 8; ++j) zo[j] = za[j];
  }
  __syncthreads();

  // ---- bilinear y1/y2: y[i] = sum_k bT[k][i] * z[k], 8 i per wave ----
  {
    float y1[8], y2[8];
#pragma unroll
    for (int j = 0; j < 8; ++j) { y1[j] = 0.f; y2[j] = 0.f; }
#pragma unroll 2
    for (int k = 0; k < 32; ++k) {
      float zv = m1s[lane][k];
      const float* q1 = bT1 + k * 32 + cz;
      const float* q2 = bT2 + k * 32 + cz;
#pragma unroll
      for (int j = 0; j < 8; ++j) { y1[j] += zv * q1[j]; y2[j] += zv * q2[j]; }
    }
    if (valid) {
#pragma unroll
      for (int j = 0; j < 8; ++j) {
        y1out[(size_t)row * 32 + cz + j] = y1[j];
        y2out[(size_t)row * 32 + cz + j] = y2[j];
      }
    }
  }

  // ---- head: fl[cf] = headb + sum_k z[k]*headW[k][cf]; 64 cols/wave, 2 passes ----
  for (int half = 0; half < 2; ++half) {
    int cf = w * 64 + half * 32;
    float f[32];
#pragma unroll
    for (int j = 0; j < 32; ++j) f[j] = headb[cf + j];
    for (int k = 0; k < 32; ++k) {
      float zv = m1s[lane][k];
      const float* hw = headW + k * 256 + cf;
#pragma unroll
      for (int j = 0; j < 32; ++j) f[j] += zv * hw[j];
    }
    if (valid) {
      float* fo = flout + (size_t)row * 256 + cf;
#pragma unroll
      for (int j = 0; j < 32; ++j) fo[j] = f[j];
    }
  }
}

// ---------------- K4b: node chain B (2 input mats, 1 bilinear) ----------------
__global__ void __launch_bounds__(256) k_nodeB(
    const float* __restrict__ x0B, const float* __restrict__ m,
    const float* __restrict__ Wl, const float* __restrict__ bl,
    const float* __restrict__ Wr, const float* __restrict__ bT,
    const float* __restrict__ projW, const float* __restrict__ projb,
    const float* __restrict__ headW, const float* __restrict__ headb,
    float* __restrict__ zout, float* __restrict__ flout,
    float* __restrict__ yout, int N) {
  __shared__ float xs[64][65];
  __shared__ float ms[64][65];
  int t = threadIdx.x;
  int lane = t & 63;
  int w = __builtin_amdgcn_readfirstlane(t >> 6);
  int row0 = blockIdx.x * 64;
  int row = row0 + lane;
  bool valid = row < N;

  for (int i = t; i < 1024; i += 256) {
    int r = i >> 4, c4 = i & 15;
    int grow = min(row0 + r, N - 1);
    float4 v1 = *((const float4*)(x0B + (size_t)grow * 64) + c4);
    float4 v2 = *((const float4*)(m + (size_t)grow * 64) + c4);
    int b = c4 * 4;
    xs[r][b] = v1.x; xs[r][b + 1] = v1.y; xs[r][b + 2] = v1.z; xs[r][b + 3] = v1.w;
    ms[r][b] = v2.x; ms[r][b + 1] = v2.y; ms[r][b + 2] = v2.z; ms[r][b + 3] = v2.w;
  }
  __syncthreads();

  int c0 = w * 16;
  float acc[16];
#pragma unroll
  for (int j = 0; j < 16; ++j) acc[j] = 0.f;
#pragma unroll 2
  for (int k = 0; k < 64; ++k) {
    float a0 = xs[lane][k], a1 = ms[lane][k];
    const float* pl = Wl + k * 64 + c0;
    const float* pr = Wr + k * 64 + c0;
#pragma unroll
    for (int j = 0; j < 16; ++j) acc[j] += a1 * pl[j] + a0 * pr[j];
  }
  __syncthreads();
#pragma unroll
  for (int j = 0; j < 16; ++j) xs[lane][c0 + j] = acc[j] + bl[c0 + j];
  __syncthreads();

  int cz = w * 8;
  float za[8];
#pragma unroll
  for (int j = 0; j < 8; ++j) za[j] = projb[cz + j];
#pragma unroll 4
  for (int k = 0; k < 64; ++k) {
    float h = xs[lane][k];
    const float* pw = projW + k * 32 + cz;
#pragma unroll
    for (int j = 0; j < 8; ++j) za[j] += h * pw[j];
  }
#pragma unroll
  for (int j = 0; j < 8; ++j) {
    za[j] = fmaxf(za[j], 0.f);
    ms[lane][cz + j] = za[j];
  }
  if (valid) {
    float* zo = zout + (size_t)row * 32 + cz;
#pragma unroll
    for (int j = 0; j < 8; ++j) zo[j] = za[j];
  }
  __syncthreads();

  {
    float y1[8];
#pragma unroll
    for (int j = 0; j < 8; ++j) y1[j] = 0.f;
#pragma unroll 2
    for (int k = 0; k < 32; ++k) {
      float zv = ms[lane][k];
      const float* q1 = bT + k * 32 + cz;
#pragma unroll
      for (int j = 0; j < 8; ++j) y1[j] += zv * q1[j];
    }
    if (valid) {
#pragma unroll
      for (int j = 0; j < 8; ++j) yout[(size_t)row * 32 + cz + j] = y1[j];
    }
  }

  for (int half = 0; half < 2; ++half) {
    int cf = w * 64 + half * 32;
    float f[32];
#pragma unroll
    for (int j = 0; j < 32; ++j) f[j] = headb[cf + j];
    for (int k = 0; k < 32; ++k) {
      float zv = ms[lane][k];
      const float* hw = headW + k * 256 + cf;
#pragma unroll
      for (int j = 0; j < 32; ++j) f[j] += zv * hw[j];
    }
    if (valid) {
      float* fo = flout + (size_t)row * 256 + cf;
#pragma unroll
      for (int j = 0; j < 32; ++j) fo[j] = f[j];
    }
  }
}

// ---------------- K5: bilinear edge scores: s = z_src . y_dst + b ----------------
__global__ void k_bil(const int* __restrict__ ei, const float* __restrict__ zsrc,
                      const float* __restrict__ ydst, const float* __restrict__ b,
                      float* __restrict__ s, int E) {
  int e = blockIdx.x * 256 + threadIdx.x;
  if (e >= E) return;
  int si = ei[e], di = ei[E + e];
  const float4* zp = (const float4*)(zsrc + (size_t)si * 32);
  const float4* yp = (const float4*)(ydst + (size_t)di * 32);
  float acc = 0.f;
#pragma unroll
  for (int i = 0; i < 8; ++i) {
    float4 a = zp[i], c = yp[i];
    acc += a.x * c.x + a.y * c.y + a.z * c.z + a.w * c.w;
  }
  s[e] = acc + b[0];
}

extern "C" void kernel_launch(void* const* d_in, const int* in_sizes, int n_in,
                              void* d_out, int out_size, void* d_ws, size_t ws_size,
                              hipStream_t stream) {
  const int* xA = (const int*)d_in[0];
  const int* xB = (const int*)d_in[1];
  const int* ei_ab = (const int*)d_in[2];
  const int* ei_ba = (const int*)d_in[3];
  const int* ei_aa = (const int*)d_in[4];
  const float* embA = (const float*)d_in[5];
  const float* embB = (const float*)d_in[6];
  const float* preWA = (const float*)d_in[7];
  const float* prebA = (const float*)d_in[8];
  const float* preWB = (const float*)d_in[9];
  const float* prebB = (const float*)d_in[10];
  const float* Wl_ab = (const float*)d_in[11];
  const float* bl_ab = (const float*)d_in[12];
  const float* Wr_ab = (const float*)d_in[13];
  const float* Wl_ba = (const float*)d_in[14];
  const float* bl_ba = (const float*)d_in[15];
  const float* Wr_ba = (const float*)d_in[16];
  const float* Wl_aa = (const float*)d_in[17];
  const float* bl_aa = (const float*)d_in[18];
  const float* Wr_aa = (const float*)d_in[19];
  const float* projWA = (const float*)d_in[20];
  const float* projbA = (const float*)d_in[21];
  const float* projWB = (const float*)d_in[22];
  const float* projbB = (const float*)d_in[23];
  const float* headWA = (const float*)d_in[24];
  const float* headbA = (const float*)d_in[25];
  const float* headWB = (const float*)d_in[26];
  const float* headbB = (const float*)d_in[27];
  const float* bilW_ab = (const float*)d_in[28];
  const float* bilb_ab = (const float*)d_in[29];
  const float* bilW_ba = (const float*)d_in[30];
  const float* bilb_ba = (const float*)d_in[31];
  const float* bilW_aa = (const float*)d_in[32];
  const float* bilb_aa = (const float*)d_in[33];

  float* out = (float*)d_out;
  float* zA = out;                      // 50000*32
  float* zB = out + 1600000;            // 50000*32
  float* flA = out + 3200000;           // 50000*256
  float* flB = out + 16000000;          // 50000*256
  float* s_ab = out + 28800000;         // 800000
  float* s_ba = out + 29600000;
  float* s_aa = out + 30400000;

  float* ws = (float*)d_ws;
  float* T = ws;                               // 32768
  float* x0A = ws + 32768;
  float* x0B = x0A + (size_t)NA * 64;
  float* mab = x0B + (size_t)NB * 64;          // dst=B
  float* mba = mab + (size_t)NB * 64;          // dst=A
  float* maa = mba + (size_t)NA * 64;          // dst=A
  float* yabB = maa + (size_t)NA * 64;
  float* ybaA = yabB + (size_t)NB * 32;
  float* yaaA = ybaA + (size_t)NA * 32;
  int* cur = (int*)(yaaA + (size_t)NA * 32);   // 150000 ints
  int* cur_ab = cur;
  int* cur_ba = cur + NB;
  int* cur_aa = cur + NB + NA;
  float* prep = (float*)(cur + 150016);        // 15424 floats
  int* slots = (int*)flA;                      // aliases fl_A (dead until k_nodeA)

  hipMemsetAsync(cur, 0, (size_t)(NA + NB + NA) * sizeof(int), stream);
  k_tables<<<128, 256, 0, stream>>>(embA, embB, preWA, preWB, T);
  k_prep<<<16, 256, 0, stream>>>(Wr_ba, Wr_aa, Wl_ba, Wl_aa, bl_ba, bl_aa,
                                 bilW_ba, bilW_aa, bilW_ab, prep);
  k_x0<<<(NA + 63) / 64, 256, 65536, stream>>>(xA, T, prebA, x0A, NA);
  k_x0<<<(NB + 63) / 64, 256, 65536, stream>>>(xB, T + 16384, prebB, x0B, NB);

  k_scatter<<<NE / 256, 256, 0, stream>>>(ei_ab, cur_ab, slots, NE);
  k_mean<<<(NB + 15) / 16, 256, 0, stream>>>(slots, cur_ab, x0A, mab, NB);
  k_scatter<<<NE / 256, 256, 0, stream>>>(ei_ba, cur_ba, slots, NE);
  k_mean<<<(NA + 15) / 16, 256, 0, stream>>>(slots, cur_ba, x0B, mba, NA);
  k_scatter<<<NE / 256, 256, 0, stream>>>(ei_aa, cur_aa, slots, NE);
  k_mean<<<(NA + 15) / 16, 256, 0, stream>>>(slots, cur_aa, x0A, maa, NA);

  k_nodeA<<<(NA + 63) / 64, 256, 0, stream>>>(
      x0A, mba, maa, prep, projWA, projbA, headWA, headbA,
      zA, flA, ybaA, yaaA, NA);
  k_nodeB<<<(NB + 63) / 64, 256, 0, stream>>>(
      x0B, mab, Wl_ab, bl_ab, Wr_ab, prep + 14400, projWB, projbB, headWB, headbB,
      zB, flB, yabB, NB);

  k_bil<<<NE / 256, 256, 0, stream>>>(ei_ab, zA, yabB, bilb_ab, s_ab, NE);
  k_bil<<<NE / 256, 256, 0, stream>>>(ei_ba, zB, ybaA, bilb_ba, s_ba, NE);
  k_bil<<<NE / 256, 256, 0, stream>>>(ei_aa, zA, yaaA, bilb_aa, s_aa, NE);
}

// Round 3
// 574.779 us; speedup vs baseline: 2.2083x; 1.2685x over previous
//
#include <hip/hip_runtime.h>

typedef unsigned short u16;
typedef unsigned int u32;
typedef __attribute__((ext_vector_type(8))) short short8;  // 8 bf16 (4 VGPRs)
typedef __attribute__((ext_vector_type(4))) float f32x4;

constexpr int NA = 50000, NB = 50000;
constexpr int EMB = 16, HID = 64;
constexpr int NE = 800000;
constexpr int CAP = 64;

#define MFMA16(a, b, c) __builtin_amdgcn_mfma_f32_16x16x32_bf16(a, b, c, 0, 0, 0)

__device__ inline u16 f2bf(float f) {  // RNE f32->bf16
  u32 b = __float_as_uint(f);
  return (u16)((b + 0x7FFFu + ((b >> 16) & 1u)) >> 16);
}
__device__ inline float bfl(u32 u) { return __uint_as_float(u << 16); }
__device__ inline float bfh(u32 u) { return __uint_as_float(u & 0xFFFF0000u); }

// ---------------- K0: fold embedding tables through pre_W (f32 out) ----------------
__global__ void k_tables(const float* __restrict__ embA, const float* __restrict__ embB,
                         const float* __restrict__ preWA, const float* __restrict__ preWB,
                         float* __restrict__ T) {
  int id = blockIdx.x * 256 + threadIdx.x;  // 0..32767
  int type = id >> 14;
  int rem = id & 16383;
  int col = rem >> 8;
  int fdbin = rem & 255;
  int fd = fdbin >> 5;
  const float* emb = type ? embB : embA;
  const float* W = type ? preWB : preWA;
  const float* e = emb + fdbin * EMB;
  const float* w = W + (fd * EMB) * HID + col;
  float s = 0.f;
#pragma unroll
  for (int j = 0; j < EMB; ++j) s += e[j] * w[j * HID];
  T[id] = s;
}

// ---------------- K0b: pack all weights into MFMA B-fragment order (bf16) ----------
// frag[f*512 + lane*8 + j] = B[k = (lane>>4)*8 + j (+32*kstep)][n = ntile*16 + (lane&15)]
// frag ids: 0..23 nodeA stage1 (K=192: 0.5*(Wr_ba+Wr_aa) | 0.5*Wl_ba | 0.5*Wl_aa)
//   24..27 projWA | 28..43 headWA | 44..45 bilW_ba^T | 46..47 bilW_aa^T
//   48..63 nodeB stage1 (K=128: Wr_ab | Wl_ab) | 64..67 projWB | 68..83 headWB | 84..85 bilW_ab^T
__global__ void k_prep(const float* __restrict__ Wr_ba, const float* __restrict__ Wr_aa,
                       const float* __restrict__ Wl_ba, const float* __restrict__ Wl_aa,
                       const float* __restrict__ Wl_ab, const float* __restrict__ Wr_ab,
                       const float* __restrict__ bl_ba, const float* __restrict__ bl_aa,
                       const float* __restrict__ projWA, const float* __restrict__ projWB,
                       const float* __restrict__ headWA, const float* __restrict__ headWB,
                       const float* __restrict__ bilW_ba, const float* __restrict__ bilW_aa,
                       const float* __restrict__ bilW_ab,
                       u16* __restrict__ frag, float* __restrict__ bhA) {
  int tid = blockIdx.x * 256 + threadIdx.x;
  if (tid >= 86 * 64) {
    int i = tid - 86 * 64;
    if (i < 64) bhA[i] = 0.5f * (bl_ba[i] + bl_aa[i]);
    return;
  }
  int f = tid >> 6, lane = tid & 63;
  int nidx = lane & 15, quad = lane >> 4;
  u16* dst = frag + (size_t)f * 512 + lane * 8;
#pragma unroll
  for (int j = 0; j < 8; ++j) {
    int kq = quad * 8 + j;
    float v;
    if (f < 24) {
      int s = f >> 2, nt = f & 3, k = s * 32 + kq, c = nt * 16 + nidx;
      v = (k < 64) ? 0.5f * (Wr_ba[k * 64 + c] + Wr_aa[k * 64 + c])
          : (k < 128) ? 0.5f * Wl_ba[(k - 64) * 64 + c]
                      : 0.5f * Wl_aa[(k - 128) * 64 + c];
    } else if (f < 28) {
      int g = f - 24, k = (g >> 1) * 32 + kq, c = (g & 1) * 16 + nidx;
      v = projWA[k * 32 + c];
    } else if (f < 44) {
      int c = (f - 28) * 16 + nidx;
      v = headWA[kq * 256 + c];
    } else if (f < 46) {
      int i2 = (f - 44) * 16 + nidx;
      v = bilW_ba[i2 * 32 + kq];
    } else if (f < 48) {
      int i2 = (f - 46) * 16 + nidx;
      v = bilW_aa[i2 * 32 + kq];
    } else if (f < 64) {
      int g = f - 48, s = g >> 2, nt = g & 3, k = s * 32 + kq, c = nt * 16 + nidx;
      v = (k < 64) ? Wr_ab[k * 64 + c] : Wl_ab[(k - 64) * 64 + c];
    } else if (f < 68) {
      int g = f - 64, k = (g >> 1) * 32 + kq, c = (g & 1) * 16 + nidx;
      v = projWB[k * 32 + c];
    } else if (f < 84) {
      int c = (f - 68) * 16 + nidx;
      v = headWB[kq * 256 + c];
    } else {
      int i2 = (f - 84) * 16 + nidx;
      v = bilW_ab[i2 * 32 + kq];
    }
    dst[j] = f2bf(v);
  }
}

// ---------------- K1: x0 = relu(bias + sum_fd T[fd][bin_fd][:]) -> bf16 ----------------
__global__ void __launch_bounds__(256) k_x0(const int* __restrict__ x,
                                            const float* __restrict__ T,
                                            const float* __restrict__ bias,
                                            u16* __restrict__ x0, int N) {
  extern __shared__ float Tl[];  // 16384 floats = 64KB
  const float4* Tg = (const float4*)T;
  float4* Ts = (float4*)Tl;
  for (int i = threadIdx.x; i < 4096; i += 256) {
    int col = i >> 6, b4 = i & 63;
    Ts[col * 64 + ((b4 + 2 * (col >> 4)) & 63)] = Tg[i];
  }
  __syncthreads();
  int t = threadIdx.x;
  int r = t >> 2, q = t & 3;
  int row = blockIdx.x * 64 + r;
  bool valid = row < N;
  int arow = valid ? row : (N - 1);
  const int4* xp = (const int4*)(x + arow * 8);
  int4 xa = xp[0], xb = xp[1];
  int bins[8] = {xa.x, xa.y, xa.z, xa.w, xb.x, xb.y, xb.z, xb.w};
  int c0 = q * 16;
  float acc[16];
#pragma unroll
  for (int j = 0; j < 16; ++j) acc[j] = bias[c0 + j];
#pragma unroll
  for (int fd = 0; fd < 8; ++fd) {
    int sb = ((fd * 32 + bins[fd]) + 8 * q) & 255;
#pragma unroll
    for (int j = 0; j < 16; ++j) acc[j] += Tl[(c0 + j) * 256 + sb];
  }
  if (valid) {
    u32 p[8];
#pragma unroll
    for (int j = 0; j < 8; ++j) {
      u16 lo = f2bf(fmaxf(acc[2 * j], 0.f));
      u16 hi = f2bf(fmaxf(acc[2 * j + 1], 0.f));
      p[j] = (u32)lo | ((u32)hi << 16);
    }
    u32* o = (u32*)(x0 + (size_t)row * 64 + c0);
    *(uint4*)o = *(uint4*)&p[0];
    *((uint4*)o + 1) = *(uint4*)&p[4];
  }
}

// ---------------- K2: fused edge scatter (3 relations) ----------------
__global__ void k_scatter_all(const int* __restrict__ ei_ab, const int* __restrict__ ei_ba,
                              const int* __restrict__ ei_aa, int* __restrict__ cur,
                              int* __restrict__ slots_ab, int* __restrict__ slots_ba,
                              int* __restrict__ slots_aa) {
  int e = blockIdx.x * 256 + threadIdx.x;  // grid is exactly 3*NE
  int rel = e / NE;
  int le = e - rel * NE;
  const int* ei = rel == 0 ? ei_ab : (rel == 1 ? ei_ba : ei_aa);
  int* slots = rel == 0 ? slots_ab : (rel == 1 ? slots_ba : slots_aa);
  int src = ei[le];
  int dstn = ei[NE + le];
  int pos = atomicAdd(cur + rel * 50000 + dstn, 1);
  if (pos < CAP) slots[(size_t)dstn * CAP + pos] = src;
}

// ---------------- K3: fused segment mean (3 relations), bf16 in/out ----------------
__global__ void k_mean_all(const int* __restrict__ slots_ab, const int* __restrict__ slots_ba,
                           const int* __restrict__ slots_aa, const int* __restrict__ cur,
                           const u16* __restrict__ x0A, const u16* __restrict__ x0B,
                           u16* __restrict__ mab, u16* __restrict__ mba,
                           u16* __restrict__ maa) {
  int t = threadIdx.x;
  int lane = t & 15, local = t >> 4;
  int d = blockIdx.x * 16 + local;  // grid exactly 150000/16
  int rel = d / 50000;
  int dstn = d - rel * 50000;
  const int* slots = rel == 0 ? slots_ab : (rel == 1 ? slots_ba : slots_aa);
  const u16* x0 = (rel == 1) ? x0B : x0A;
  u16* out = rel == 0 ? mab : (rel == 1 ? mba : maa);
  int deg = cur[d];
  int cnt = min(deg, CAP);
  const int* sl = slots + (size_t)dstn * CAP;
  float a0 = 0.f, a1 = 0.f, a2 = 0.f, a3 = 0.f;
  for (int i = 0; i < cnt; ++i) {
    int src = sl[i];
    uint2 v = *(const uint2*)(x0 + (size_t)src * 64 + lane * 4);
    a0 += bfl(v.x); a1 += bfh(v.x); a2 += bfl(v.y); a3 += bfh(v.y);
  }
  float inv = 1.f / (float)max(deg, 1);
  u32 lo = (u32)f2bf(a0 * inv) | ((u32)f2bf(a1 * inv) << 16);
  u32 hi = (u32)f2bf(a2 * inv) | ((u32)f2bf(a3 * inv) << 16);
  *(uint2*)(out + (size_t)dstn * 64 + lane * 4) = make_uint2(lo, hi);
}

// ---------------- K4a: MFMA node chain A ----------------
// 4 waves/block, each wave owns 32 rows; no __syncthreads anywhere.
__global__ void __launch_bounds__(256) k_nodeA(
    const u16* __restrict__ x0, const u16* __restrict__ m1, const u16* __restrict__ m2,
    const u16* __restrict__ frag, const float* __restrict__ bhA,
    const float* __restrict__ projb, const float* __restrict__ headb,
    float* __restrict__ zout, float* __restrict__ flout,
    u16* __restrict__ zbf, u16* __restrict__ y1bf, u16* __restrict__ y2bf, int N) {
  __shared__ u16 lds[4][3584];  // per-wave: h 32x72, z 32x40
  int t = threadIdx.x, lane = t & 63, w = t >> 6;
  u16* hld = &lds[w][0];
  u16* zld = &lds[w][2304];
  int rows0 = blockIdx.x * 128 + w * 32;
  int nidx = lane & 15, quad = lane >> 4;
  size_t r0 = (size_t)min(rows0 + nidx, N - 1);
  size_t r1 = (size_t)min(rows0 + 16 + nidx, N - 1);

  // ---- stage 1: h = [x0|m1|m2] @ Wcat (K=192) ----
  f32x4 acc[2][4];
#pragma unroll
  for (int mt = 0; mt < 2; ++mt)
#pragma unroll
    for (int nt = 0; nt < 4; ++nt) acc[mt][nt] = {0.f, 0.f, 0.f, 0.f};
  const u16* mats[3] = {x0, m1, m2};
#pragma unroll
  for (int s = 0; s < 6; ++s) {
    const u16* src = mats[s >> 1];
    int koff = (s & 1) * 32 + quad * 8;
    short8 a0 = *(const short8*)(src + r0 * 64 + koff);
    short8 a1 = *(const short8*)(src + r1 * 64 + koff);
#pragma unroll
    for (int nt = 0; nt < 4; ++nt) {
      short8 b = *(const short8*)(frag + (size_t)(s * 4 + nt) * 512 + lane * 8);
      acc[0][nt] = MFMA16(a0, b, acc[0][nt]);
      acc[1][nt] = MFMA16(a1, b, acc[1][nt]);
    }
  }
#pragma unroll
  for (int mt = 0; mt < 2; ++mt)
#pragma unroll
    for (int nt = 0; nt < 4; ++nt) {
      int col = nt * 16 + nidx;
      float bb = bhA[col];
#pragma unroll
      for (int r2 = 0; r2 < 4; ++r2)
        hld[(mt * 16 + quad * 4 + r2) * 72 + col] = f2bf(acc[mt][nt][r2] + bb);
    }

  // ---- stage 2: z = relu(h @ projW + b) ----
  f32x4 zacc[2][2];
#pragma unroll
  for (int mt = 0; mt < 2; ++mt)
#pragma unroll
    for (int nt = 0; nt < 2; ++nt) zacc[mt][nt] = {0.f, 0.f, 0.f, 0.f};
#pragma unroll
  for (int s = 0; s < 2; ++s) {
    short8 a0 = *(const short8*)(hld + nidx * 72 + s * 32 + quad * 8);
    short8 a1 = *(const short8*)(hld + (16 + nidx) * 72 + s * 32 + quad * 8);
#pragma unroll
    for (int nt = 0; nt < 2; ++nt) {
      short8 b = *(const short8*)(frag + (size_t)(24 + s * 2 + nt) * 512 + lane * 8);
      zacc[0][nt] = MFMA16(a0, b, zacc[0][nt]);
      zacc[1][nt] = MFMA16(a1, b, zacc[1][nt]);
    }
  }
#pragma unroll
  for (int mt = 0; mt < 2; ++mt)
#pragma unroll
    for (int nt = 0; nt < 2; ++nt) {
      int col = nt * 16 + nidx;
      float pb = projb[col];
#pragma unroll
      for (int r2 = 0; r2 < 4; ++r2) {
        int rl = mt * 16 + quad * 4 + r2;
        float zv = fmaxf(zacc[mt][nt][r2] + pb, 0.f);
        zld[rl * 40 + col] = f2bf(zv);
        int grow = rows0 + rl;
        if (grow < N) zout[(size_t)grow * 32 + col] = zv;
      }
    }
  {  // coalesced bf16 z store (2 lanes per row)
    int rl = lane >> 1, hf = lane & 1;
    int grow = rows0 + rl;
    if (grow < N) {
      short8 v0 = *(const short8*)(zld + rl * 40 + hf * 16);
      short8 v1 = *(const short8*)(zld + rl * 40 + hf * 16 + 8);
      *(short8*)(zbf + (size_t)grow * 32 + hf * 16) = v0;
      *(short8*)(zbf + (size_t)grow * 32 + hf * 16 + 8) = v1;
    }
  }

  // ---- stage 3: y1/y2 = z @ bilW^T ----
  short8 az0 = *(const short8*)(zld + nidx * 40 + quad * 8);
  short8 az1 = *(const short8*)(zld + (16 + nidx) * 40 + quad * 8);
#pragma unroll
  for (int mat = 0; mat < 2; ++mat) {
    f32x4 ya[2][2];
#pragma unroll
    for (int mt = 0; mt < 2; ++mt)
#pragma unroll
      for (int nt = 0; nt < 2; ++nt) ya[mt][nt] = {0.f, 0.f, 0.f, 0.f};
#pragma unroll
    for (int nt = 0; nt < 2; ++nt) {
      short8 b = *(const short8*)(frag + (size_t)(44 + mat * 2 + nt) * 512 + lane * 8);
      ya[0][nt] = MFMA16(az0, b, ya[0][nt]);
      ya[1][nt] = MFMA16(az1, b, ya[1][nt]);
    }
#pragma unroll
    for (int mt = 0; mt < 2; ++mt)
#pragma unroll
      for (int nt = 0; nt < 2; ++nt)
#pragma unroll
        for (int r2 = 0; r2 < 4; ++r2)
          hld[(mt * 16 + quad * 4 + r2) * 40 + nt * 16 + nidx] = f2bf(ya[mt][nt][r2]);
    u16* yo = mat ? y2bf : y1bf;
    int rl = lane >> 1, hf = lane & 1;
    int grow = rows0 + rl;
    if (grow < N) {
      short8 v0 = *(const short8*)(hld + rl * 40 + hf * 16);
      short8 v1 = *(const short8*)(hld + rl * 40 + hf * 16 + 8);
      *(short8*)(yo + (size_t)grow * 32 + hf * 16) = v0;
      *(short8*)(yo + (size_t)grow * 32 + hf * 16 + 8) = v1;
    }
  }

  // ---- stage 4: fl = z @ headW + b (256 cols in 4 chunks) ----
  for (int chunk = 0; chunk < 4; ++chunk) {
    f32x4 fa[2][4];
#pragma unroll
    for (int mt = 0; mt < 2; ++mt)
#pragma unroll
      for (int nt = 0; nt < 4; ++nt) fa[mt][nt] = {0.f, 0.f, 0.f, 0.f};
#pragma unroll
    for (int nt = 0; nt < 4; ++nt) {
      short8 b = *(const short8*)(frag + (size_t)(28 + chunk * 4 + nt) * 512 + lane * 8);
      fa[0][nt] = MFMA16(az0, b, fa[0][nt]);
      fa[1][nt] = MFMA16(az1, b, fa[1][nt]);
    }
#pragma unroll
    for (int mt = 0; mt < 2; ++mt)
#pragma unroll
      for (int nt = 0; nt < 4; ++nt) {
        int col = chunk * 64 + nt * 16 + nidx;
        float hb = headb[col];
#pragma unroll
        for (int r2 = 0; r2 < 4; ++r2) {
          int grow = rows0 + mt * 16 + quad * 4 + r2;
          if (grow < N) flout[(size_t)grow * 256 + col] = fa[mt][nt][r2] + hb;
        }
      }
  }
}

// ---------------- K4b: MFMA node chain B ----------------
__global__ void __launch_bounds__(256) k_nodeB(
    const u16* __restrict__ x0, const u16* __restrict__ m1,
    const u16* __restrict__ frag, const float* __restrict__ blB,
    const float* __restrict__ projb, const float* __restrict__ headb,
    float* __restrict__ zout, float* __restrict__ flout,
    u16* __restrict__ zbf, u16* __restrict__ ybf, int N) {
  __shared__ u16 lds[4][3584];
  int t = threadIdx.x, lane = t & 63, w = t >> 6;
  u16* hld = &lds[w][0];
  u16* zld = &lds[w][2304];
  int rows0 = blockIdx.x * 128 + w * 32;
  int nidx = lane & 15, quad = lane >> 4;
  size_t r0 = (size_t)min(rows0 + nidx, N - 1);
  size_t r1 = (size_t)min(rows0 + 16 + nidx, N - 1);

  f32x4 acc[2][4];
#pragma unroll
  for (int mt = 0; mt < 2; ++mt)
#pragma unroll
    for (int nt = 0; nt < 4; ++nt) acc[mt][nt] = {0.f, 0.f, 0.f, 0.f};
#pragma unroll
  for (int s = 0; s < 4; ++s) {
    const u16* src = (s < 2) ? x0 : m1;
    int koff = (s & 1) * 32 + quad * 8;
    short8 a0 = *(const short8*)(src + r0 * 64 + koff);
    short8 a1 = *(const short8*)(src + r1 * 64 + koff);
#pragma unroll
    for (int nt = 0; nt < 4; ++nt) {
      short8 b = *(const short8*)(frag + (size_t)(48 + s * 4 + nt) * 512 + lane * 8);
      acc[0][nt] = MFMA16(a0, b, acc[0][nt]);
      acc[1][nt] = MFMA16(a1, b, acc[1][nt]);
    }
  }
#pragma unroll
  for (int mt = 0; mt < 2; ++mt)
#pragma unroll
    for (int nt = 0; nt < 4; ++nt) {
      int col = nt * 16 + nidx;
      float bb = blB[col];
#pragma unroll
      for (int r2 = 0; r2 < 4; ++r2)
        hld[(mt * 16 + quad * 4 + r2) * 72 + col] = f2bf(acc[mt][nt][r2] + bb);
    }

  f32x4 zacc[2][2];
#pragma unroll
  for (int mt = 0; mt < 2; ++mt)
#pragma unroll
    for (int nt = 0; nt < 2; ++nt) zacc[mt][nt] = {0.f, 0.f, 0.f, 0.f};
#pragma unroll
  for (int s = 0; s < 2; ++s) {
    short8 a0 = *(const short8*)(hld + nidx * 72 + s * 32 + quad * 8);
    short8 a1 = *(const short8*)(hld + (16 + nidx) * 72 + s * 32 + quad * 8);
#pragma unroll
    for (int nt = 0; nt < 2; ++nt) {
      short8 b = *(const short8*)(frag + (size_t)(64 + s * 2 + nt) * 512 + lane * 8);
      zacc[0][nt] = MFMA16(a0, b, zacc[0][nt]);
      zacc[1][nt] = MFMA16(a1, b, zacc[1][nt]);
    }
  }
#pragma unroll
  for (int mt = 0; mt < 2; ++mt)
#pragma unroll
    for (int nt = 0; nt < 2; ++nt) {
      int col = nt * 16 + nidx;
      float pb = projb[col];
#pragma unroll
      for (int r2 = 0; r2 < 4; ++r2) {
        int rl = mt * 16 + quad * 4 + r2;
        float zv = fmaxf(zacc[mt][nt][r2] + pb, 0.f);
        zld[rl * 40 + col] = f2bf(zv);
        int grow = rows0 + rl;
        if (grow < N) zout[(size_t)grow * 32 + col] = zv;
      }
    }
  {
    int rl = lane >> 1, hf = lane & 1;
    int grow = rows0 + rl;
    if (grow < N) {
      short8 v0 = *(const short8*)(zld + rl * 40 + hf * 16);
      short8 v1 = *(const short8*)(zld + rl * 40 + hf * 16 + 8);
      *(short8*)(zbf + (size_t)grow * 32 + hf * 16) = v0;
      *(short8*)(zbf + (size_t)grow * 32 + hf * 16 + 8) = v1;
    }
  }

  short8 az0 = *(const short8*)(zld + nidx * 40 + quad * 8);
  short8 az1 = *(const short8*)(zld + (16 + nidx) * 40 + quad * 8);
  {
    f32x4 ya[2][2];
#pragma unroll
    for (int mt = 0; mt < 2; ++mt)
#pragma unroll
      for (int nt = 0; nt < 2; ++nt) ya[mt][nt] = {0.f, 0.f, 0.f, 0.f};
#pragma unroll
    for (int nt = 0; nt < 2; ++nt) {
      short8 b = *(const short8*)(frag + (size_t)(84 + nt) * 512 + lane * 8);
      ya[0][nt] = MFMA16(az0, b, ya[0][nt]);
      ya[1][nt] = MFMA16(az1, b, ya[1][nt]);
    }
#pragma unroll
    for (int mt = 0; mt < 2; ++mt)
#pragma unroll
      for (int nt = 0; nt < 2; ++nt)
#pragma unroll
        for (int r2 = 0; r2 < 4; ++r2)
          hld[(mt * 16 + quad * 4 + r2) * 40 + nt * 16 + nidx] = f2bf(ya[mt][nt][r2]);
    int rl = lane >> 1, hf = lane & 1;
    int grow = rows0 + rl;
    if (grow < N) {
      short8 v0 = *(const short8*)(hld + rl * 40 + hf * 16);
      short8 v1 = *(const short8*)(hld + rl * 40 + hf * 16 + 8);
      *(short8*)(ybf + (size_t)grow * 32 + hf * 16) = v0;
      *(short8*)(ybf + (size_t)grow * 32 + hf * 16 + 8) = v1;
    }
  }

  for (int chunk = 0; chunk < 4; ++chunk) {
    f32x4 fa[2][4];
#pragma unroll
    for (int mt = 0; mt < 2; ++mt)
#pragma unroll
      for (int nt = 0; nt < 4; ++nt) fa[mt][nt] = {0.f, 0.f, 0.f, 0.f};
#pragma unroll
    for (int nt = 0; nt < 4; ++nt) {
      short8 b = *(const short8*)(frag + (size_t)(68 + chunk * 4 + nt) * 512 + lane * 8);
      fa[0][nt] = MFMA16(az0, b, fa[0][nt]);
      fa[1][nt] = MFMA16(az1, b, fa[1][nt]);
    }
#pragma unroll
    for (int mt = 0; mt < 2; ++mt)
#pragma unroll
      for (int nt = 0; nt < 4; ++nt) {
        int col = chunk * 64 + nt * 16 + nidx;
        float hb = headb[col];
#pragma unroll
        for (int r2 = 0; r2 < 4; ++r2) {
          int grow = rows0 + mt * 16 + quad * 4 + r2;
          if (grow < N) flout[(size_t)grow * 256 + col] = fa[mt][nt][r2] + hb;
        }
      }
  }
}

// ---------------- K5: fused bilinear edge scores (3 relations) ----------------
__global__ void k_bil_all(const int* __restrict__ ei_ab, const int* __restrict__ ei_ba,
                          const int* __restrict__ ei_aa,
                          const u16* __restrict__ zA, const u16* __restrict__ zB,
                          const u16* __restrict__ yab, const u16* __restrict__ yba,
                          const u16* __restrict__ yaa,
                          const float* __restrict__ b_ab, const float* __restrict__ b_ba,
                          const float* __restrict__ b_aa,
                          float* __restrict__ s_ab, float* __restrict__ s_ba,
                          float* __restrict__ s_aa) {
  int e = blockIdx.x * 256 + threadIdx.x;  // grid exactly 3*NE
  int rel = e / NE;
  int le = e - rel * NE;
  const int* ei = rel == 0 ? ei_ab : (rel == 1 ? ei_ba : ei_aa);
  const u16* zs = (rel == 1) ? zB : zA;
  const u16* yd = rel == 0 ? yab : (rel == 1 ? yba : yaa);
  const float* bb = rel == 0 ? b_ab : (rel == 1 ? b_ba : b_aa);
  float* so = rel == 0 ? s_ab : (rel == 1 ? s_ba : s_aa);
  int si = ei[le], di = ei[NE + le];
  const uint4* zp = (const uint4*)(zs + (size_t)si * 32);
  const uint4* yp = (const uint4*)(yd + (size_t)di * 32);
  float acc = 0.f;
#pragma unroll
  for (int i = 0; i < 2; ++i) {
    uint4 a = zp[i], c = yp[i];
    acc += bfl(a.x) * bfl(c.x) + bfh(a.x) * bfh(c.x);
    acc += bfl(a.y) * bfl(c.y) + bfh(a.y) * bfh(c.y);
    acc += bfl(a.z) * bfl(c.z) + bfh(a.z) * bfh(c.z);
    acc += bfl(a.w) * bfl(c.w) + bfh(a.w) * bfh(c.w);
  }
#pragma unroll
  for (int i = 2; i < 4; ++i) {
    uint4 a = zp[i], c = yp[i];
    acc += bfl(a.x) * bfl(c.x) + bfh(a.x) * bfh(c.x);
    acc += bfl(a.y) * bfl(c.y) + bfh(a.y) * bfh(c.y);
    acc += bfl(a.z) * bfl(c.z) + bfh(a.z) * bfh(c.z);
    acc += bfl(a.w) * bfl(c.w) + bfh(a.w) * bfh(c.w);
  }
  so[le] = acc + bb[0];
}

extern "C" void kernel_launch(void* const* d_in, const int* in_sizes, int n_in,
                              void* d_out, int out_size, void* d_ws, size_t ws_size,
                              hipStream_t stream) {
  const int* xA = (const int*)d_in[0];
  const int* xB = (const int*)d_in[1];
  const int* ei_ab = (const int*)d_in[2];
  const int* ei_ba = (const int*)d_in[3];
  const int* ei_aa = (const int*)d_in[4];
  const float* embA = (const float*)d_in[5];
  const float* embB = (const float*)d_in[6];
  const float* preWA = (const float*)d_in[7];
  const float* prebA = (const float*)d_in[8];
  const float* preWB = (const float*)d_in[9];
  const float* prebB = (const float*)d_in[10];
  const float* Wl_ab = (const float*)d_in[11];
  const float* bl_ab = (const float*)d_in[12];
  const float* Wr_ab = (const float*)d_in[13];
  const float* Wl_ba = (const float*)d_in[14];
  const float* bl_ba = (const float*)d_in[15];
  const float* Wr_ba = (const float*)d_in[16];
  const float* Wl_aa = (const float*)d_in[17];
  const float* bl_aa = (const float*)d_in[18];
  const float* Wr_aa = (const float*)d_in[19];
  const float* projWA = (const float*)d_in[20];
  const float* projbA = (const float*)d_in[21];
  const float* projWB = (const float*)d_in[22];
  const float* projbB = (const float*)d_in[23];
  const float* headWA = (const float*)d_in[24];
  const float* headbA = (const float*)d_in[25];
  const float* headWB = (const float*)d_in[26];
  const float* headbB = (const float*)d_in[27];
  const float* bilW_ab = (const float*)d_in[28];
  const float* bilb_ab = (const float*)d_in[29];
  const float* bilW_ba = (const float*)d_in[30];
  const float* bilb_ba = (const float*)d_in[31];
  const float* bilW_aa = (const float*)d_in[32];
  const float* bilb_aa = (const float*)d_in[33];

  float* out = (float*)d_out;
  float* zA = out;                      // 50000*32
  float* zB = out + 1600000;            // 50000*32
  float* flA = out + 3200000;           // 50000*256
  float* flB = out + 16000000;          // 50000*256
  float* s_ab = out + 28800000;
  float* s_ba = out + 29600000;
  float* s_aa = out + 30400000;

  // workspace (byte offsets, all 16B-aligned)
  char* ws = (char*)d_ws;
  float* T = (float*)(ws + 0);            // 131072 B
  u16* x0Abf = (u16*)(ws + 131072);       // 6.4e6 B
  u16* x0Bbf = (u16*)(ws + 6531072);
  u16* mabbf = (u16*)(ws + 12931072);
  u16* mbabf = (u16*)(ws + 19331072);
  u16* maabf = (u16*)(ws + 25731072);
  u16* zAbf = (u16*)(ws + 32131072);      // 3.2e6 B
  u16* zBbf = (u16*)(ws + 35331072);
  u16* yabbf = (u16*)(ws + 38531072);
  u16* ybabf = (u16*)(ws + 41731072);
  u16* yaabf = (u16*)(ws + 44931072);
  int* cur = (int*)(ws + 48131072);       // 600000 B
  u16* frag = (u16*)(ws + 48731072);      // 88064 B
  float* bhA = (float*)(ws + 48819136);   // 256 B

  // slot buckets alias fl_A's d_out region (dead until k_nodeA runs)
  int* slots_ab = (int*)flA;
  int* slots_ba = slots_ab + (size_t)50000 * CAP;
  int* slots_aa = slots_ba + (size_t)50000 * CAP;

  hipMemsetAsync(cur, 0, 150000 * sizeof(int), stream);
  k_tables<<<128, 256, 0, stream>>>(embA, embB, preWA, preWB, T);
  k_prep<<<22, 256, 0, stream>>>(Wr_ba, Wr_aa, Wl_ba, Wl_aa, Wl_ab, Wr_ab,
                                 bl_ba, bl_aa, projWA, projWB, headWA, headWB,
                                 bilW_ba, bilW_aa, bilW_ab, frag, bhA);
  k_x0<<<(NA + 63) / 64, 256, 65536, stream>>>(xA, T, prebA, x0Abf, NA);
  k_x0<<<(NB + 63) / 64, 256, 65536, stream>>>(xB, T + 16384, prebB, x0Bbf, NB);

  k_scatter_all<<<3 * NE / 256, 256, 0, stream>>>(ei_ab, ei_ba, ei_aa, cur,
                                                  slots_ab, slots_ba, slots_aa);
  k_mean_all<<<150000 / 16, 256, 0, stream>>>(slots_ab, slots_ba, slots_aa, cur,
                                              x0Abf, x0Bbf, mabbf, mbabf, maabf);

  k_nodeA<<<(NA + 127) / 128, 256, 0, stream>>>(
      x0Abf, mbabf, maabf, frag, bhA, projbA, headbA,
      zA, flA, zAbf, ybabf, yaabf, NA);
  k_nodeB<<<(NB + 127) / 128, 256, 0, stream>>>(
      x0Bbf, mabbf, frag, bl_ab, projbB, headbB,
      zB, flB, zBbf, yabbf, NB);

  k_bil_all<<<3 * NE / 256, 256, 0, stream>>>(ei_ab, ei_ba, ei_aa, zAbf, zBbf,
                                              yabbf, ybabf, yaabf,
                                              bilb_ab, bilb_ba, bilb_aa,
                                              s_ab, s_ba, s_aa);
}